// Round 1
// baseline (343.558 us; speedup 1.0000x reference)
//
#include <hip/hip_runtime.h>

#define NXMITS 128
#define NELEMS 128
#define NSAMPS 2048
#define NX     128
#define NZ     1024
#define PI_F   3.14159265359f
#define MIN_W  0.001f

// One thread per output pixel (line, z). Walks the 128 receive elements
// sequentially so the cumsum-based Hamming rank is a simple running counter.
// Pass 1: mask bits + M (no memory traffic). Pass 2: gather+interp+rotate
// only for masked elements (apod==0 elsewhere => exact skip).
__global__ __launch_bounds__(256) void das_kernel(
    const float* __restrict__ idata,
    const float* __restrict__ qdata,
    const float* __restrict__ grid,
    const float* __restrict__ rx_ori,
    const float* __restrict__ ele_pos,
    const float* __restrict__ tstart,
    const float* __restrict__ cptr,
    const float* __restrict__ fsptr,
    const float* __restrict__ fdptr,
    const float* __restrict__ fnptr,
    float* __restrict__ out)
{
    __shared__ float s_ele[NELEMS * 3];
    const int tid = threadIdx.x;
    for (int i = tid; i < NELEMS * 3; i += blockDim.x) s_ele[i] = ele_pos[i];
    __syncthreads();

    const int line = blockIdx.y;
    const int z    = blockIdx.x * blockDim.x + tid;

    const float c      = cptr[0];
    const float fs     = fsptr[0];
    const float fdemod = fdptr[0];
    const float fnum   = fnptr[0];
    const float ts     = tstart[line];   // dl[line] == line (nx == nxmits)

    const float* gp = grid + ((size_t)line * NZ + z) * 3;
    const float gx = gp[0], gy = gp[1], gz = gp[2];
    const float rox = rx_ori[line * 3 + 0];
    const float roy = rx_ori[line * 3 + 1];
    const float roz = rx_ori[line * 3 + 2];
    const float dxp = gx - rox, dyp = gy - roy, dzp = gz - roz;
    const float txdel = sqrtf(dxp * dxp + dyp * dyp + dzp * dzp);

    const float* iline = idata + (size_t)line * NELEMS * NSAMPS;
    const float* qline = qdata + (size_t)line * NELEMS * NSAMPS;

    // ---- pass 1: apodization mask + count ----
    unsigned long long m0 = 0ull, m1 = 0ull;
    int M = 0;
    for (int e = 0; e < NELEMS; ++e) {
        const float vx = gx - s_ele[e * 3 + 0];
        const float vz = gz - s_ele[e * 3 + 2];
        // match reference: (|vz/vx| >= fnum) | (|vx| <= MIN_WIDTH); vx==0 -> inf -> true
        const bool mask = (fabsf(vz / vx) >= fnum) || (fabsf(vx) <= MIN_W);
        if (mask) {
            ++M;
            if (e < 64) m0 |= (1ull << e); else m1 |= (1ull << (e - 64));
        }
    }
    const float Msafe  = (float)max(M, 1);
    const bool  useham = (M > 1);

    const float two_gz_c = gz * 2.0f / c;         // g_z*2.0/c, ref order
    const float w2pi_fd  = 2.0f * PI_F * fdemod;  // (2*pi)*fdemod, ref order

    float isum = 0.0f, qsum = 0.0f;
    int rank = -1;

    // ---- pass 2: gather + interp + rotate + hamming ----
    for (int e = 0; e < NELEMS; ++e) {
        const bool mask = (e < 64) ? ((m0 >> e) & 1ull) : ((m1 >> (e - 64)) & 1ull);
        if (!mask) continue;
        ++rank;

        const float ex = s_ele[e * 3 + 0];
        const float ey = s_ele[e * 3 + 1];
        const float ez = s_ele[e * 3 + 2];
        const float vx = gx - ex, vy = gy - ey, vz = gz - ez;
        const float rxdel = sqrtf(vx * vx + vy * vy + vz * vz);

        const float delays = ((txdel + rxdel) / c - ts) * fs;
        const float s0 = floorf(delays);
        const float w  = delays - s0;
        const int   i0 = (int)s0;
        const int   i1 = i0 + 1;

        const float* ib = iline + (size_t)e * NSAMPS;
        const float* qb = qline + (size_t)e * NSAMPS;
        float iv0 = 0.0f, iv1 = 0.0f, qv0 = 0.0f, qv1 = 0.0f;
        if (i0 >= 0 && i0 < NSAMPS) { iv0 = ib[i0]; qv0 = qb[i0]; }
        if (i1 >= 0 && i1 < NSAMPS) { iv1 = ib[i1]; qv1 = qb[i1]; }

        float ifoc = iv0 * (1.0f - w) + iv1 * w;
        float qfoc = qv0 * (1.0f - w) + qv1 * w;

        const float tshift = delays / fs - two_gz_c;
        const float theta  = w2pi_fd * tshift;
        float st, ct;
        sincosf(theta, &st, &ct);           // precise version (theta can be ~100 rad)
        const float ir = ifoc * ct - qfoc * st;
        const float qr = qfoc * ct + ifoc * st;
        if (fdemod != 0.0f) { ifoc = ir; qfoc = qr; }

        const float apod = useham
            ? (0.54f - 0.46f * cosf(2.0f * PI_F * (float)rank / Msafe))
            : 1.0f;
        isum += ifoc * apod;
        qsum += qfoc * apod;
    }

    out[(size_t)line * NZ + z]                    = isum;
    out[(size_t)NX * NZ + (size_t)line * NZ + z]  = qsum;
}

extern "C" void kernel_launch(void* const* d_in, const int* in_sizes, int n_in,
                              void* d_out, int out_size, void* d_ws, size_t ws_size,
                              hipStream_t stream) {
    const float* idata   = (const float*)d_in[0];
    const float* qdata   = (const float*)d_in[1];
    const float* grid    = (const float*)d_in[2];
    const float* rx_ori  = (const float*)d_in[3];
    const float* ele_pos = (const float*)d_in[4];
    const float* tstart  = (const float*)d_in[5];
    const float* c       = (const float*)d_in[6];
    const float* fs      = (const float*)d_in[7];
    const float* fdemod  = (const float*)d_in[8];
    const float* rxfnum  = (const float*)d_in[9];
    float* out = (float*)d_out;

    dim3 block(256);
    dim3 grd(NZ / 256, NX);
    das_kernel<<<grd, block, 0, stream>>>(idata, qdata, grid, rx_ori, ele_pos,
                                          tstart, c, fs, fdemod, rxfnum, out);
}

// Round 2
// 264.250 us; speedup vs baseline: 1.3001x; 1.3001x over previous
//
#include <hip/hip_runtime.h>

#define NELEMS 128
#define NSAMPS 2048
#define NX     128
#define NZ     1024
#define PI_F   3.14159265359f
#define MIN_W  0.001f

// Block = (64 z-pixels, 4 element-chunks). Each thread handles 32 receive
// elements for one pixel. Chunk masks exchanged via LDS to reconstruct the
// exact cumsum-based Hamming rank; partial sums reduced via LDS.
// Fast sincos is safe: masked elements have |theta| <= ~96 rad, where
// __sincosf's abs error is ~1e-5 (threshold 0.445). The mask comparison
// keeps exact IEEE division (discontinuous); /c and /fs become reciprocal
// multiplies (continuous effect only).
__global__ __launch_bounds__(256) void das_kernel(
    const float* __restrict__ idata,
    const float* __restrict__ qdata,
    const float* __restrict__ grid,
    const float* __restrict__ rx_ori,
    const float* __restrict__ ele_pos,
    const float* __restrict__ tstart,
    const float* __restrict__ cptr,
    const float* __restrict__ fsptr,
    const float* __restrict__ fdptr,
    const float* __restrict__ fnptr,
    float* __restrict__ out)
{
    __shared__ float s_ele[NELEMS * 3];
    __shared__ unsigned int s_mask[4][64];
    __shared__ float s_i[4][64];
    __shared__ float s_q[4][64];

    const int tx  = threadIdx.x;          // z-pixel lane within block (0..63)
    const int ty  = threadIdx.y;          // element chunk (0..3) == wave id
    const int tid = ty * 64 + tx;
    for (int i = tid; i < NELEMS * 3; i += 256) s_ele[i] = ele_pos[i];
    __syncthreads();

    const int line = blockIdx.y;
    const int z    = blockIdx.x * 64 + tx;

    const float c      = cptr[0];
    const float fs     = fsptr[0];
    const float fdemod = fdptr[0];
    const float fnum   = fnptr[0];
    const float ts     = tstart[line];    // dl[line] == line (nx == nxmits)

    const float* gp = grid + ((size_t)line * NZ + z) * 3;
    const float gx = gp[0], gy = gp[1], gz = gp[2];
    const float rox = rx_ori[line * 3 + 0];
    const float roy = rx_ori[line * 3 + 1];
    const float roz = rx_ori[line * 3 + 2];
    const float dxp = gx - rox, dyp = gy - roy, dzp = gz - roz;
    const float txdel = sqrtf(dxp * dxp + dyp * dyp + dzp * dzp);

    const float inv_c = 1.0f / c;
    const int ebase = ty * 32;

    // ---- pass 1: this chunk's apodization mask (exact IEEE division) ----
    unsigned int word = 0;
    for (int j = 0; j < 32; ++j) {
        const float vx = gx - s_ele[(ebase + j) * 3 + 0];
        const float vz = gz - s_ele[(ebase + j) * 3 + 2];
        const bool mask = (fabsf(vz / vx) >= fnum) || (fabsf(vx) <= MIN_W);
        word |= mask ? (1u << j) : 0u;
    }
    s_mask[ty][tx] = word;
    __syncthreads();

    const unsigned int w0 = s_mask[0][tx];
    const unsigned int w1 = s_mask[1][tx];
    const unsigned int w2 = s_mask[2][tx];
    const unsigned int w3 = s_mask[3][tx];
    const int M = __popc(w0) + __popc(w1) + __popc(w2) + __popc(w3);
    int rankbase = 0;
    if (ty > 0) rankbase += __popc(w0);
    if (ty > 1) rankbase += __popc(w1);
    if (ty > 2) rankbase += __popc(w2);

    const float Msafe   = (float)(M > 1 ? M : 1);
    const bool  useham  = (M > 1);
    const float w2pi_M  = 2.0f * PI_F / Msafe;        // rank * this = 2*pi*rank/Msafe
    const float two_gz_c = gz * 2.0f / c;
    const float w2pi_fd  = 2.0f * PI_F * fdemod;

    const float* iline = idata + ((size_t)line * NELEMS + ebase) * NSAMPS;
    const float* qline = qdata + ((size_t)line * NELEMS + ebase) * NSAMPS;

    float isum = 0.0f, qsum = 0.0f;
    int rank = rankbase - 1;

    // ---- pass 2: gather + interp + rotate + hamming, masked only ----
    for (int j = 0; j < 32; ++j) {
        if (!((word >> j) & 1u)) continue;
        ++rank;

        const int e = ebase + j;
        const float ex = s_ele[e * 3 + 0];
        const float ey = s_ele[e * 3 + 1];
        const float ez = s_ele[e * 3 + 2];
        const float vx = gx - ex, vy = gy - ey, vz = gz - ez;
        const float rxdel = sqrtf(vx * vx + vy * vy + vz * vz);

        const float d      = (txdel + rxdel) * inv_c;   // seconds (delays/fs)
        const float delays = (d - ts) * fs;
        const float s0 = floorf(delays);
        const float w  = delays - s0;
        const int   i0 = (int)s0;
        const int   i1 = i0 + 1;

        const float* ib = iline + (size_t)j * NSAMPS;
        const float* qb = qline + (size_t)j * NSAMPS;
        float iv0 = 0.0f, iv1 = 0.0f, qv0 = 0.0f, qv1 = 0.0f;
        if (i0 >= 0 && i0 < NSAMPS) { iv0 = ib[i0]; qv0 = qb[i0]; }
        if (i1 >= 0 && i1 < NSAMPS) { iv1 = ib[i1]; qv1 = qb[i1]; }

        float ifoc = iv0 * (1.0f - w) + iv1 * w;
        float qfoc = qv0 * (1.0f - w) + qv1 * w;

        const float tshift = d - ts - two_gz_c;          // delays/fs - 2*gz/c
        const float theta  = w2pi_fd * tshift;           // |theta| <= ~96 rad
        float st, ct;
        __sincosf(theta, &st, &ct);
        const float ir = ifoc * ct - qfoc * st;
        const float qr = qfoc * ct + ifoc * st;
        if (fdemod != 0.0f) { ifoc = ir; qfoc = qr; }

        const float apod = useham
            ? (0.54f - 0.46f * __cosf((float)rank * w2pi_M))
            : 1.0f;
        isum = fmaf(ifoc, apod, isum);
        qsum = fmaf(qfoc, apod, qsum);
    }

    // ---- reduce the 4 chunk partials ----
    s_i[ty][tx] = isum;
    s_q[ty][tx] = qsum;
    __syncthreads();
    if (ty == 0) {
        const float it = s_i[0][tx] + s_i[1][tx] + s_i[2][tx] + s_i[3][tx];
        const float qt = s_q[0][tx] + s_q[1][tx] + s_q[2][tx] + s_q[3][tx];
        out[(size_t)line * NZ + z]                   = it;
        out[(size_t)NX * NZ + (size_t)line * NZ + z] = qt;
    }
}

extern "C" void kernel_launch(void* const* d_in, const int* in_sizes, int n_in,
                              void* d_out, int out_size, void* d_ws, size_t ws_size,
                              hipStream_t stream) {
    const float* idata   = (const float*)d_in[0];
    const float* qdata   = (const float*)d_in[1];
    const float* grid    = (const float*)d_in[2];
    const float* rx_ori  = (const float*)d_in[3];
    const float* ele_pos = (const float*)d_in[4];
    const float* tstart  = (const float*)d_in[5];
    const float* c       = (const float*)d_in[6];
    const float* fs      = (const float*)d_in[7];
    const float* fdemod  = (const float*)d_in[8];
    const float* rxfnum  = (const float*)d_in[9];
    float* out = (float*)d_out;

    dim3 block(64, 4);
    dim3 grd(NZ / 64, NX);
    das_kernel<<<grd, block, 0, stream>>>(idata, qdata, grid, rx_ori, ele_pos,
                                          tstart, c, fs, fdemod, rxfnum, out);
}